// Round 6
// baseline (367.429 us; speedup 1.0000x reference)
//
#include <hip/hip_runtime.h>
#include <hip/hip_cooperative_groups.h>
#include <math.h>

namespace cg = cooperative_groups;

#define BATCH 64
#define IMH 512
#define IMW 512
#define UNITS 256

__device__ __forceinline__ float sigmoidf_(float x) {
    return 1.0f / (1.0f + __expf(-x));
}
__device__ __forceinline__ float tanhf_(float x) {
    float e = __expf(2.0f * x);
    return 1.0f - 2.0f / (e + 1.0f);
}

// ws layout (floats): ws_x [64*256] | ws_z [64*1024]
#define WS_X 0
#define WS_Z 16384

// One cooperative kernel, 256 blocks x 256 threads (1 block/CU).
// P0: blocks 0..63  -> interp + conv1 + conv2 + dense  -> ws_x
// P1: all 256 blocks -> LSTM pre-activations z          -> ws_z
// P2: blocks 0..63  -> cell + nsc1 + nsc2               -> out
__global__ __launch_bounds__(256) void fused_coop(
    const float* __restrict__ image, const float* __restrict__ section,
    const float* __restrict__ h0, const float* __restrict__ c0,
    const float* __restrict__ k1, const float* __restrict__ b1,
    const float* __restrict__ k2, const float* __restrict__ b2,
    const float* __restrict__ dw, const float* __restrict__ db,
    const float* __restrict__ lk, const float* __restrict__ lrk,
    const float* __restrict__ lb, const float* __restrict__ w1,
    const float* __restrict__ nb1, const float* __restrict__ w2,
    const float* __restrict__ nb2, float* __restrict__ out,
    float* __restrict__ ws)
{
    cg::grid_group grid = cg::this_grid();
    const int bx  = blockIdx.x;
    const int tid = threadIdx.x;

    __shared__ float s_sec[16][16][3];
    __shared__ float s_c1[14][14][3];
    __shared__ float s_flat[432];
    __shared__ float s_k1[84];
    __shared__ float s_k2[84];
    __shared__ float s_pf[1024];      // 4 ks x 64 quads x float4 (reused)
    __shared__ float s_x4[4][256];    // P1
    __shared__ float s_h4[4][256];    // P1
    __shared__ float s_zpf[1024];     // P1: (ks*4+bb)*16+q float4
    __shared__ float s_hn[256];       // P2
    __shared__ float s_nsc[256];      // P2

    // ================= P0: front (blocks 0..63, one per batch) =================
    if (bx < 64) {
        const int b = bx;

        if (tid < 81)       s_k1[tid]      = k1[tid];
        else if (tid < 84)  s_k1[tid]      = b1[tid - 81];
        else if (tid < 165) s_k2[tid - 84] = k2[tid - 84];
        else if (tid < 168) s_k2[tid - 84] = b2[tid - 165];

        // bilinear interp: 16x16 grid, one thread per grid point
        {
            const float s0 = section[b * 3 + 0];
            const float s1 = section[b * 3 + 1];
            const float s2 = section[b * 3 + 2];
            const int i = tid >> 4, j = tid & 15;
            float p0 = s0 + (float)i * (1.0f / 15.0f) * s2;
            float p1 = s1 + (float)j * (1.0f / 15.0f) * s2;
            float fy = fminf(fmaxf(p0 * 511.0f, 0.0f), 511.0f);
            float fx = fminf(fmaxf(p1 * 511.0f, 0.0f), 511.0f);
            int y0 = (int)floorf(fy);
            int x0 = (int)floorf(fx);
            int y1 = min(y0 + 1, 511);
            int x1 = min(x0 + 1, 511);
            float wy = fy - (float)y0;
            float wx = fx - (float)x0;
            const float* base = image + (size_t)b * IMH * IMW * 3;
            const float* p00 = base + (y0 * IMW + x0) * 3;
            const float* p01 = base + (y0 * IMW + x1) * 3;
            const float* p10 = base + (y1 * IMW + x0) * 3;
            const float* p11 = base + (y1 * IMW + x1) * 3;
            #pragma unroll
            for (int c = 0; c < 3; ++c) {
                float top = p00[c] * (1.0f - wx) + p01[c] * wx;
                float bot = p10[c] * (1.0f - wx) + p11[c] * wx;
                s_sec[i][j][c] = top * (1.0f - wy) + bot * wy;
            }
        }
        __syncthreads();

        // conv1: 16x16 -> 14x14
        if (tid < 196) {
            const int i = tid / 14, j = tid % 14;
            float a0 = s_k1[81], a1 = s_k1[82], a2 = s_k1[83];
            #pragma unroll
            for (int di = 0; di < 3; ++di)
                #pragma unroll
                for (int dj = 0; dj < 3; ++dj)
                    #pragma unroll
                    for (int ci = 0; ci < 3; ++ci) {
                        float v = s_sec[i + di][j + dj][ci];
                        const int kb = ((di * 3 + dj) * 3 + ci) * 3;
                        a0 += v * s_k1[kb + 0];
                        a1 += v * s_k1[kb + 1];
                        a2 += v * s_k1[kb + 2];
                    }
            s_c1[i][j][0] = fmaxf(a0, 0.0f);
            s_c1[i][j][1] = fmaxf(a1, 0.0f);
            s_c1[i][j][2] = fmaxf(a2, 0.0f);
        }
        __syncthreads();

        // conv2: 14x14 -> 12x12, flatten
        if (tid < 144) {
            const int i = tid / 12, j = tid % 12;
            float a0 = s_k2[81], a1 = s_k2[82], a2 = s_k2[83];
            #pragma unroll
            for (int di = 0; di < 3; ++di)
                #pragma unroll
                for (int dj = 0; dj < 3; ++dj)
                    #pragma unroll
                    for (int ci = 0; ci < 3; ++ci) {
                        float v = s_c1[i + di][j + dj][ci];
                        const int kb = ((di * 3 + dj) * 3 + ci) * 3;
                        a0 += v * s_k2[kb + 0];
                        a1 += v * s_k2[kb + 1];
                        a2 += v * s_k2[kb + 2];
                    }
            const int fb = tid * 3;
            s_flat[fb + 0] = fmaxf(a0, 0.0f);
            s_flat[fb + 1] = fmaxf(a1, 0.0f);
            s_flat[fb + 2] = fmaxf(a2, 0.0f);
        }
        __syncthreads();

        // dense 432->256: thread = (ks of 4, col-quad q of 64); 108 float4, unroll 27
        {
            const int ks = tid >> 6;
            const int q  = tid & 63;
            const int k0 = ks * 108;
            const float4* wp = (const float4*)dw + (size_t)k0 * 64 + q;
            const float* fp = s_flat + k0;
            float4 acc = {0.f, 0.f, 0.f, 0.f};
            #pragma unroll 27
            for (int k = 0; k < 108; ++k) {
                const float4 w = wp[k * 64];
                const float v = fp[k];
                acc.x += v * w.x; acc.y += v * w.y; acc.z += v * w.z; acc.w += v * w.w;
            }
            ((float4*)s_pf)[ks * 64 + q] = acc;
        }
        __syncthreads();
        {
            // s_pf float-index (ks*64+q2)*4+comp == ks*256 + tid  (conflict-free)
            float a = db[tid];
            #pragma unroll
            for (int ks2 = 0; ks2 < 4; ++ks2)
                a += s_pf[ks2 * 256 + tid];
            ws[WS_X + b * 256 + tid] = fmaxf(a, 0.0f);
        }
    }

    grid.sync();

    // ================= P1: LSTM z = x@lk + h0@lrk + lb (all 256 blocks) =========
    {
        const int ct    = bx & 15;       // col tile (64 cols)
        const int bt    = bx >> 4;       // batch tile (4 rows)
        const int col0  = ct * 64;
        const int colq0 = ct * 16;
        const int row0  = bt * 4;

        for (int i = tid; i < 1024; i += 256) {
            const int r = i >> 8, k = i & 255;
            s_x4[r][k] = ws[WS_X + (row0 + r) * 256 + k];
            s_h4[r][k] = h0[(row0 + r) * 256 + k];
        }
        __syncthreads();

        {
            const int q  = tid & 15;
            const int bb = (tid >> 4) & 3;
            const int ks = tid >> 6;         // 0..3, chunk 64
            const int k0 = ks * 64;
            const float4* lkp = (const float4*)lk  + (size_t)k0 * 256 + colq0 + q;
            const float4* lrp = (const float4*)lrk + (size_t)k0 * 256 + colq0 + q;
            const float* xp = s_x4[bb] + k0;
            const float* hp = s_h4[bb] + k0;
            float4 acc = {0.f, 0.f, 0.f, 0.f};
            #pragma unroll 16
            for (int k = 0; k < 64; ++k) {
                const float4 a = lkp[k * 256];
                const float4 r = lrp[k * 256];
                const float xv = xp[k];
                const float hv = hp[k];
                acc.x += xv * a.x + hv * r.x;
                acc.y += xv * a.y + hv * r.y;
                acc.z += xv * a.z + hv * r.z;
                acc.w += xv * a.w + hv * r.w;
            }
            ((float4*)s_zpf)[(ks * 4 + bb) * 16 + q] = acc;
        }
        __syncthreads();

        {
            const int c   = tid & 63;
            const int bb2 = tid >> 6;
            const int q2 = c >> 2, comp = c & 3;
            float z = lb[col0 + c];
            #pragma unroll
            for (int ks2 = 0; ks2 < 4; ++ks2)
                z += s_zpf[((ks2 * 4 + bb2) * 16 + q2) * 4 + comp];
            ws[WS_Z + (row0 + bb2) * 1024 + col0 + c] = z;
        }
    }

    grid.sync();

    // ================= P2: cell + nsc1 + nsc2 (blocks 0..63, one per batch) =====
    if (bx < 64) {
        const int b = bx;

        // LSTM pointwise cell
        {
            const int u = tid;
            const float zi = ws[WS_Z + b * 1024 + u];
            const float zf = ws[WS_Z + b * 1024 + 256 + u];
            const float zg = ws[WS_Z + b * 1024 + 512 + u];
            const float zo = ws[WS_Z + b * 1024 + 768 + u];
            const float cprev = c0[b * 256 + u];
            const float cn = sigmoidf_(zf) * cprev + sigmoidf_(zi) * tanhf_(zg);
            const float hn = sigmoidf_(zo) * tanhf_(cn);
            out[b * 256 + u] = hn;                       // h_new
            out[BATCH * UNITS + b * 256 + u] = cn;       // c_new
            s_hn[u] = hn;
        }
        __syncthreads();

        // nsc1 256->256 + relu: thread = (ks of 4, col-quad q of 64); 64 float4
        {
            const int ks = tid >> 6;
            const int q  = tid & 63;
            const int k0 = ks * 64;
            const float4* wp = (const float4*)w1 + (size_t)k0 * 64 + q;
            const float* hp = s_hn + k0;
            float4 acc = {0.f, 0.f, 0.f, 0.f};
            #pragma unroll 16
            for (int k = 0; k < 64; ++k) {
                const float4 w = wp[k * 64];
                const float v = hp[k];
                acc.x += v * w.x; acc.y += v * w.y; acc.z += v * w.z; acc.w += v * w.w;
            }
            ((float4*)s_pf)[ks * 64 + q] = acc;
        }
        __syncthreads();
        {
            float a = nb1[tid];
            #pragma unroll
            for (int ks2 = 0; ks2 < 4; ++ks2)
                a += s_pf[ks2 * 256 + tid];
            s_nsc[tid] = fmaxf(a, 0.0f);
        }
        __syncthreads();

        // nsc2 256->3 + sigmoid: wave j reduces output column j
        if (tid < 192) {
            const int j = tid >> 6;
            const int l = tid & 63;
            float p = 0.0f;
            #pragma unroll
            for (int k = l; k < 256; k += 64)
                p += s_nsc[k] * w2[k * 3 + j];
            #pragma unroll
            for (int off = 32; off > 0; off >>= 1)
                p += __shfl_down(p, off);
            if (l == 0)
                out[2 * BATCH * UNITS + b * 3 + j] = sigmoidf_(p + nb2[j]);
        }
    }
}

extern "C" void kernel_launch(void* const* d_in, const int* in_sizes, int n_in,
                              void* d_out, int out_size, void* d_ws, size_t ws_size,
                              hipStream_t stream) {
    const float* image   = (const float*)d_in[0];
    const float* section = (const float*)d_in[1];
    const float* h0      = (const float*)d_in[2];
    const float* c0      = (const float*)d_in[3];
    const float* k1      = (const float*)d_in[4];
    const float* b1      = (const float*)d_in[5];
    const float* k2      = (const float*)d_in[6];
    const float* b2      = (const float*)d_in[7];
    const float* dw      = (const float*)d_in[8];
    const float* db      = (const float*)d_in[9];
    const float* lk      = (const float*)d_in[10];
    const float* lrk     = (const float*)d_in[11];
    const float* lb      = (const float*)d_in[12];
    const float* w1      = (const float*)d_in[13];
    const float* nb1     = (const float*)d_in[14];
    const float* w2      = (const float*)d_in[15];
    const float* nb2     = (const float*)d_in[16];
    float* out = (float*)d_out;
    float* ws  = (float*)d_ws;

    void* args[] = {
        (void*)&image, (void*)&section, (void*)&h0, (void*)&c0,
        (void*)&k1, (void*)&b1, (void*)&k2, (void*)&b2,
        (void*)&dw, (void*)&db, (void*)&lk, (void*)&lrk, (void*)&lb,
        (void*)&w1, (void*)&nb1, (void*)&w2, (void*)&nb2,
        (void*)&out, (void*)&ws
    };
    hipLaunchCooperativeKernel((const void*)fused_coop,
                               dim3(256), dim3(256), args, 0, stream);
}

// Round 7
// 299.177 us; speedup vs baseline: 1.2281x; 1.2281x over previous
//
#include <hip/hip_runtime.h>
#include <math.h>

#define BATCH 64
#define IMH 512
#define IMW 512
#define UNITS 256

__device__ __forceinline__ float sigmoidf_(float x) {
    return 1.0f / (1.0f + __expf(-x));
}
__device__ __forceinline__ float tanhf_(float x) {
    float e = __expf(2.0f * x);
    return 1.0f - 2.0f / (e + 1.0f);
}

__global__ __launch_bounds__(1024) void fused_cell_kernel(
    const float* __restrict__ image,    // (64,512,512,3)
    const float* __restrict__ section,  // (64,3)
    const float* __restrict__ h0,       // (64,256)
    const float* __restrict__ c0,       // (64,256)
    const float* __restrict__ k1,       // (3,3,3,3)
    const float* __restrict__ b1,       // (3,)
    const float* __restrict__ k2,       // (3,3,3,3)
    const float* __restrict__ b2,       // (3,)
    const float* __restrict__ dw,       // (432,256)
    const float* __restrict__ db,       // (256,)
    const float* __restrict__ lk,       // (256,1024)
    const float* __restrict__ lrk,      // (256,1024)
    const float* __restrict__ lb,       // (1024,)
    const float* __restrict__ w1,       // (256,256)
    const float* __restrict__ nb1,      // (256,)
    const float* __restrict__ w2,       // (256,3)
    const float* __restrict__ nb2,      // (3,)
    float* __restrict__ out)            // h_new(64,256) | c_new(64,256) | next_section(64,3)
{
    const int b   = blockIdx.x;
    const int tid = threadIdx.x;

    __shared__ float s_sec[16][16][3];   // interpolated section
    __shared__ float s_c1[14][14][3];    // conv1 output
    __shared__ float s_flat[432];        // conv2 output, flattened (i*12+j)*3+c
    __shared__ float s_x[256];           // dense output
    __shared__ float s_h0[256];
    __shared__ float s_hn[256];
    __shared__ float s_nsc[256];
    __shared__ float s_z[1024];          // LSTM pre-activations
    __shared__ float s_part[4][256];     // K-split partial sums
    __shared__ float s_k1[84];           // 81 conv1 weights + 3 bias
    __shared__ float s_k2[84];           // 81 conv2 weights + 3 bias

    // ---- stage small weights & h0 ----
    if (tid < 81)       s_k1[tid]      = k1[tid];
    else if (tid < 84)  s_k1[tid]      = b1[tid - 81];
    else if (tid < 165) s_k2[tid - 84] = k2[tid - 84];
    else if (tid < 168) s_k2[tid - 84] = b2[tid - 165];
    if (tid < 256) s_h0[tid] = h0[b * UNITS + tid];

    // ---- bilinear interpolation: 16x16 grid, one thread per grid point ----
    if (tid < 256) {
        const float s0 = section[b * 3 + 0];
        const float s1 = section[b * 3 + 1];
        const float s2 = section[b * 3 + 2];
        const int i = tid >> 4, j = tid & 15;
        float p0 = s0 + (float)i * (1.0f / 15.0f) * s2;
        float p1 = s1 + (float)j * (1.0f / 15.0f) * s2;
        float fy = fminf(fmaxf(p0 * 511.0f, 0.0f), 511.0f);
        float fx = fminf(fmaxf(p1 * 511.0f, 0.0f), 511.0f);
        int y0 = (int)floorf(fy);
        int x0 = (int)floorf(fx);
        int y1 = min(y0 + 1, 511);
        int x1 = min(x0 + 1, 511);
        float wy = fy - (float)y0;
        float wx = fx - (float)x0;
        const float* base = image + (size_t)b * IMH * IMW * 3;
        const float* p00 = base + (y0 * IMW + x0) * 3;
        const float* p01 = base + (y0 * IMW + x1) * 3;
        const float* p10 = base + (y1 * IMW + x0) * 3;
        const float* p11 = base + (y1 * IMW + x1) * 3;
        #pragma unroll
        for (int c = 0; c < 3; ++c) {
            float top = p00[c] * (1.0f - wx) + p01[c] * wx;
            float bot = p10[c] * (1.0f - wx) + p11[c] * wx;
            s_sec[i][j][c] = top * (1.0f - wy) + bot * wy;
        }
    }
    __syncthreads();

    // ---- conv1 (3x3 VALID, 3->3 ch) + relu : 16x16 -> 14x14 ----
    if (tid < 196) {
        const int i = tid / 14, j = tid % 14;
        float a0 = s_k1[81], a1 = s_k1[82], a2 = s_k1[83];
        #pragma unroll
        for (int di = 0; di < 3; ++di)
            #pragma unroll
            for (int dj = 0; dj < 3; ++dj)
                #pragma unroll
                for (int ci = 0; ci < 3; ++ci) {
                    float v = s_sec[i + di][j + dj][ci];
                    const int kb = ((di * 3 + dj) * 3 + ci) * 3;
                    a0 += v * s_k1[kb + 0];
                    a1 += v * s_k1[kb + 1];
                    a2 += v * s_k1[kb + 2];
                }
        s_c1[i][j][0] = fmaxf(a0, 0.0f);
        s_c1[i][j][1] = fmaxf(a1, 0.0f);
        s_c1[i][j][2] = fmaxf(a2, 0.0f);
    }
    __syncthreads();

    // ---- conv2 (3x3 VALID, 3->3 ch) + relu : 14x14 -> 12x12, flatten ----
    if (tid < 144) {
        const int i = tid / 12, j = tid % 12;
        float a0 = s_k2[81], a1 = s_k2[82], a2 = s_k2[83];
        #pragma unroll
        for (int di = 0; di < 3; ++di)
            #pragma unroll
            for (int dj = 0; dj < 3; ++dj)
                #pragma unroll
                for (int ci = 0; ci < 3; ++ci) {
                    float v = s_c1[i + di][j + dj][ci];
                    const int kb = ((di * 3 + dj) * 3 + ci) * 3;
                    a0 += v * s_k2[kb + 0];
                    a1 += v * s_k2[kb + 1];
                    a2 += v * s_k2[kb + 2];
                }
        const int fb = tid * 3;   // (i*12+j)*3
        s_flat[fb + 0] = fmaxf(a0, 0.0f);
        s_flat[fb + 1] = fmaxf(a1, 0.0f);
        s_flat[fb + 2] = fmaxf(a2, 0.0f);
    }
    __syncthreads();

    // ---- dense 432 -> 256 + relu : 4-way K split (432 = 4*108) ----
    {
        const int g = tid >> 8, col = tid & 255;
        const float* wp = dw + (g * 108) * 256 + col;
        const float* fp = s_flat + g * 108;
        float acc = 0.0f;
        #pragma unroll 6
        for (int k = 0; k < 108; ++k)
            acc += fp[k] * wp[k * 256];
        s_part[g][col] = acc;
    }
    __syncthreads();
    if (tid < 256)
        s_x[tid] = fmaxf(s_part[0][tid] + s_part[1][tid] + s_part[2][tid] +
                         s_part[3][tid] + db[tid], 0.0f);
    __syncthreads();

    // ---- LSTM: z = x@lk + h0@lrk + lb ; thread t owns gate column t of 1024 ----
    {
        float z = lb[tid];
        const float* lkp = lk  + tid;
        const float* lrp = lrk + tid;
        #pragma unroll 8
        for (int k = 0; k < 256; ++k)
            z += s_x[k] * lkp[k * 1024] + s_h0[k] * lrp[k * 1024];
        s_z[tid] = z;
    }
    __syncthreads();
    if (tid < 256) {
        const float zi = s_z[tid];
        const float zf = s_z[256 + tid];
        const float zg = s_z[512 + tid];
        const float zo = s_z[768 + tid];
        const float cprev = c0[b * UNITS + tid];
        const float cn = sigmoidf_(zf) * cprev + sigmoidf_(zi) * tanhf_(zg);
        const float hn = sigmoidf_(zo) * tanhf_(cn);
        out[b * UNITS + tid] = hn;                      // h_new
        out[BATCH * UNITS + b * UNITS + tid] = cn;      // c_new
        s_hn[tid] = hn;
    }
    __syncthreads();

    // ---- nsc layer 1: 256 -> 256 + relu : 4-way K split (256 = 4*64) ----
    {
        const int g = tid >> 8, col = tid & 255;
        const float* wp = w1 + (g * 64) * 256 + col;
        const float* hp = s_hn + g * 64;
        float acc = 0.0f;
        #pragma unroll 8
        for (int k = 0; k < 64; ++k)
            acc += hp[k] * wp[k * 256];
        s_part[g][col] = acc;
    }
    __syncthreads();
    if (tid < 256)
        s_nsc[tid] = fmaxf(s_part[0][tid] + s_part[1][tid] + s_part[2][tid] +
                           s_part[3][tid] + nb1[tid], 0.0f);
    __syncthreads();

    // ---- nsc layer 2: 256 -> 3, sigmoid. One wave per output column. ----
    if (tid < 192) {
        const int j = tid >> 6;      // output column 0..2
        const int l = tid & 63;      // lane within wave
        float p = 0.0f;
        #pragma unroll
        for (int k = l; k < 256; k += 64)
            p += s_nsc[k] * w2[k * 3 + j];
        #pragma unroll
        for (int off = 32; off > 0; off >>= 1)
            p += __shfl_down(p, off);
        if (l == 0)
            out[2 * BATCH * UNITS + b * 3 + j] = sigmoidf_(p + nb2[j]);
    }
}

extern "C" void kernel_launch(void* const* d_in, const int* in_sizes, int n_in,
                              void* d_out, int out_size, void* d_ws, size_t ws_size,
                              hipStream_t stream) {
    const float* image   = (const float*)d_in[0];
    const float* section = (const float*)d_in[1];
    const float* h0      = (const float*)d_in[2];
    const float* c0      = (const float*)d_in[3];
    const float* k1      = (const float*)d_in[4];
    const float* b1      = (const float*)d_in[5];
    const float* k2      = (const float*)d_in[6];
    const float* b2      = (const float*)d_in[7];
    const float* dw      = (const float*)d_in[8];
    const float* db      = (const float*)d_in[9];
    const float* lk      = (const float*)d_in[10];
    const float* lrk     = (const float*)d_in[11];
    const float* lb      = (const float*)d_in[12];
    const float* w1      = (const float*)d_in[13];
    const float* nb1     = (const float*)d_in[14];
    const float* w2      = (const float*)d_in[15];
    const float* nb2     = (const float*)d_in[16];
    float* out = (float*)d_out;

    fused_cell_kernel<<<BATCH, 1024, 0, stream>>>(
        image, section, h0, c0, k1, b1, k2, b2, dw, db,
        lk, lrk, lb, w1, nb1, w2, nb2, out);
}